// Round 8
// baseline (737.608 us; speedup 1.0000x reference)
//
#include <hip/hip_runtime.h>
#include <math.h>

#define BB 4
#define CC 64
#define OO 64
#define HH 128
#define WWD 128
#define HWP (HH*WWD)   // 16384

// LDS window: 32 channels x 12 rows x 42 cols (tile 2x32, halo 5 all sides).
#define WROWS 12
#define WCOLS 42
#define CSTR  506            // 12*42=504 +2 pad: 8*506 mod 32 == 16 -> 2-way (free)
#define WINSZ (32 * CSTR)    // 16192 f32 = 64768 B static LDS

typedef short bf16x8 __attribute__((ext_vector_type(8)));
typedef float f32x4  __attribute__((ext_vector_type(4)));

__device__ __forceinline__ unsigned short bf16_rne(float f) {
    unsigned u = __float_as_uint(f);
    u += 0x7fffu + ((u >> 16) & 1u);
    return (unsigned short)(u >> 16);
}
__device__ __forceinline__ float bf16_tof(unsigned short h) {
    return __uint_as_float((unsigned)h << 16);
}
__device__ __forceinline__ bf16x8 ldw16(const unsigned short* p) {
    bf16x8 r; __builtin_memcpy(&r, p, 16); return r;
}

// ---------------------------------------------------------------------------
// Kernel 1: W[o][c][3][3] fp32 -> Whi/Wlo[k][o][c] bf16 (hi/lo split) for
// both layers. grid: 288 x 256 = 73728 = 2 * 64*64*9
// ---------------------------------------------------------------------------
__global__ __launch_bounds__(256) void wtrans_kernel(
    const float* __restrict__ W1, const float* __restrict__ W2,
    unsigned short* __restrict__ Wh1, unsigned short* __restrict__ Wl1,
    unsigned short* __restrict__ Wh2, unsigned short* __restrict__ Wl2)
{
    int idx = blockIdx.x * 256 + threadIdx.x;
    const int n = OO * CC * 9;           // 36864
    const float* src;
    unsigned short *dh, *dl;
    if (idx >= n) { src = W2; dh = Wh2; dl = Wl2; idx -= n; }
    else          { src = W1; dh = Wh1; dl = Wl1; }
    int c = idx & 63;
    int o = (idx >> 6) & 63;
    int k = idx >> 12;
    float w = src[(o * CC + c) * 9 + k];
    unsigned short hi = bf16_rne(w);
    unsigned short lo = bf16_rne(w - bf16_tof(hi));
    dh[idx] = hi;
    dl[idx] = lo;
}

#define MFMA(a, bfr, c) __builtin_amdgcn_mfma_f32_16x16x32_bf16(a, bfr, c, 0, 0, 0)

// ---------------------------------------------------------------------------
// One tap, one channel-half: bilinear-sample 8 channels of this lane's pixel
// from the LDS window, hi/lo split, 12 MFMAs (K=32 triple for 4 o-tiles).
// Window slot s holds image row clamp(ybase+s); reading slot R-ybase returns
// row R for ANY clamped R in [0,127] -> boundary-exact. Row/col ranges proven
// from rf<9: slot in [0,11], col in [0,41]. x-clamp at col 127 folded into
// weights (w01+=w00) -- identical algebra to the R6-verified combine.
// ---------------------------------------------------------------------------
template<int DY, int DX>
__device__ __forceinline__ void tap_step(
    const float* wq, int yg, int xg, int ybase, int xcb,
    float fy, float fx, float rh, float rw,
    const unsigned short* wh, const unsigned short* wl,
    f32x4& acc0, f32x4& acc1, f32x4& acc2, f32x4& acc3)
{
    float wy0 = 1.f, wy1 = 0.f;
    int r0, r1;
    if (DY == 0) {
        r0 = r1 = (yg - ybase) * WCOLS;
    } else {
        float ys = fy + (float)DY * rh;
        float y0f = floorf(ys);
        float ty = ys - y0f;                 // raw-floor fraction (matches ref)
        int iy0 = (int)y0f;
        int R0 = min(max(iy0, 0), HH - 1);
        int R1 = min(R0 + 1, HH - 1);
        r0 = (R0 - ybase) * WCOLS;
        r1 = (R1 - ybase) * WCOLS;
        wy0 = 1.f - ty; wy1 = ty;
    }
    float wx0 = 1.f, wx1 = 0.f;
    int c0;
    if (DX == 0) {
        c0 = xg - xcb;
    } else {
        float xs = fx + (float)DX * rw;
        float x0f = floorf(xs);
        float tx = xs - x0f;
        int ix0 = min(max((int)x0f, 0), WWD - 1);
        int ix0c = min(ix0, WWD - 2);
        wx0 = 1.f - tx; wx1 = tx;
        if (ix0 == WWD - 1) { wx1 += wx0; wx0 = 0.f; }
        c0 = ix0c - xcb;
    }
    float w00 = wy0 * wx0, w01 = wy0 * wx1;
    float w10 = wy1 * wx0, w11 = wy1 * wx1;

    union { unsigned short h[8]; bf16x8 v; } uh, ul;
#pragma unroll
    for (int j = 0; j < 8; ++j) {
        const float* pj = wq + j * CSTR;
        float s;
        if (DY == 0 && DX == 0) {
            s = pj[r0 + c0];                 // exact center value
        } else if (DY == 0) {
            s = w00 * pj[r0 + c0] + w01 * pj[r0 + c0 + 1];
        } else if (DX == 0) {
            s = w00 * pj[r0 + c0] + w10 * pj[r1 + c0];
        } else {
            s = w00 * pj[r0 + c0] + w01 * pj[r0 + c0 + 1]
              + w10 * pj[r1 + c0] + w11 * pj[r1 + c0 + 1];
        }
        unsigned short hs = bf16_rne(s);
        uh.h[j] = hs;
        ul.h[j] = bf16_rne(s - bf16_tof(hs));
    }
    bf16x8 bh = uh.v, bl = ul.v;

    bf16x8 ah0 = ldw16(wh),        al0 = ldw16(wl);
    bf16x8 ah1 = ldw16(wh + 1024), al1 = ldw16(wl + 1024);
    bf16x8 ah2 = ldw16(wh + 2048), al2 = ldw16(wl + 2048);
    bf16x8 ah3 = ldw16(wh + 3072), al3 = ldw16(wl + 3072);
    acc0 = MFMA(ah0, bh, acc0); acc0 = MFMA(al0, bh, acc0); acc0 = MFMA(ah0, bl, acc0);
    acc1 = MFMA(ah1, bh, acc1); acc1 = MFMA(al1, bh, acc1); acc1 = MFMA(ah1, bl, acc1);
    acc2 = MFMA(ah2, bh, acc2); acc2 = MFMA(al2, bh, acc2); acc2 = MFMA(ah2, bl, acc2);
    acc3 = MFMA(ah3, bh, acc3); acc3 = MFMA(al3, bh, acc3); acc3 = MFMA(ah3, bl, acc3);
}

// ---------------------------------------------------------------------------
// Kernel 2: fused offsets-conv + arconv with a 2x32-tile LDS window.
// grid: 1024 blocks x 256 threads (4 waves). XCD-chunked swizzle.
//
// R4-R6: scattered-global gathers are latency-bound (~600-900cy) and no
// 1-stage pipeline at low occupancy covers them. R7: 1x64 tiles made the
// window geometrically infeasible (needs 7x74/ch) and shipped a too-narrow
// 72-col window (OOW reads at tile right edge -> absmax 1.77).
// Fix: 2x32 pixel tiles -> halo 5 on all sides -> window 12x42 per channel.
// One window serves ALL 9 taps of a channel-half: stage(ch 0..31), sync,
// 9 taps (ks=0), sync, stage(ch 32..63), sync, 9 taps (ks=1). 3 barriers.
// Every bilinear sample is an LDS read (~120cy fixed); staging is 63 dense
// coalesced loads/thread. Lane mapping: pixel = wv*16+nidx (row p>>5, col
// p&31), channels quad*8..+8 (+32) -- the exact mfma B-fragment, no
// redistribution. Bank math: quad stride 8*506 == 16 mod 32 -> 2-way (free).
// mode 1: out = relu(acc + bias). mode 2: out = resid + acc + bias.
// ---------------------------------------------------------------------------
__global__ __launch_bounds__(256, 2) void arconv_kernel(
    const float*          __restrict__ xin,   // [B,C,H,W]
    const unsigned short* __restrict__ Whi,   // [9][O][C] bf16 hi
    const unsigned short* __restrict__ Wlo,   // [9][O][C] bf16 lo
    const float*          __restrict__ bias,
    const float*          __restrict__ woff,  // [2][C][3][3]
    const float*          __restrict__ boff,  // [2]
    const int* __restrict__ lo_p, const int* __restrict__ hi_p,
    const float* __restrict__ resid,
    float* __restrict__ out, int mode)
{
    __shared__ float win[WINSZ];   // 64768 B -> 2 blocks/CU

    int t    = threadIdx.x;
    int bid  = blockIdx.x;
    // XCD-chunked swizzle (R1: FETCH 123MB -> 9.6MB). 128 blks/XCD = 64
    // contiguous rows (~2 MB working set, fits 4 MB L2).
    int blk  = ((bid & 7) << 7) | (bid >> 3);
    int b    = blk >> 8;
    int tile = blk & 255;          // 64 ty x 4 tx
    int y0   = (tile >> 2) * 2;
    int x0   = (tile & 3) * 32;
    int ybase = y0 - 5;
    int xcb   = x0 - 5;

    int lane = t & 63;
    int wv   = t >> 6;
    int nidx = lane & 15;
    int quad = lane >> 4;
    int pix  = wv * 16 + nidx;            // 0..63 within tile
    int pr   = pix >> 5;                  // 0..1
    int pc   = pix & 31;                  // 0..31
    int yg   = y0 + pr;
    int xg   = x0 + pc;
    float fy = (float)yg;
    float fx = (float)xg;

    const float* xb_ptr = xin + (size_t)b * CC * HWP;

    // ---- phase A: offsets conv (rf), barrier-free, direct-global (R6) ----
    float a0 = 0.f, a1 = 0.f;
    {
#pragma unroll 4
        for (int ci = 0; ci < 16; ++ci) {
            int c = quad * 16 + ci;
            const float* xc = xb_ptr + (size_t)c * HWP;
            const float* w0 = woff + c * 9;
            const float* w1 = woff + (CC + c) * 9;
#pragma unroll
            for (int ky = 0; ky < 3; ++ky) {
                int yy = yg + ky - 1;
                bool yok = (yy >= 0) && (yy < HH);
#pragma unroll
                for (int kx = 0; kx < 3; ++kx) {
                    int xx = xg + kx - 1;
                    float v = 0.f;
                    if (yok && xx >= 0 && xx < WWD) v = xc[yy * WWD + xx];
                    a0 = fmaf(v, w0[ky * 3 + kx], a0);
                    a1 = fmaf(v, w1[ky * 3 + kx], a1);
                }
            }
        }
        a0 += __shfl_xor(a0, 16); a0 += __shfl_xor(a0, 32);
        a1 += __shfl_xor(a1, 16); a1 += __shfl_xor(a1, 32);
    }
    float flo = (float)lo_p[0];
    float fhi = (float)hi_p[0];
    float rh = (flo + (fhi - flo) / (1.f + expf(-(a0 + boff[0])))) * 0.5f;
    float rw = (flo + (fhi - flo) / (1.f + expf(-(a1 + boff[1])))) * 0.5f;

    const float* wq = win + quad * 8 * CSTR;             // lane's ch-run base
    const int fragel = nidx * CC + quad * 8;             // A-frag base (elems)
    f32x4 acc0 = {}, acc1 = {}, acc2 = {}, acc3 = {};

    // Dense window staging: 32*12*42 = 16128 f32 = 63/thread, coalesced runs.
#define STAGEW(H) do { \
        const float* xsrc_ = xb_ptr + (size_t)((H) * 32) * HWP; \
        _Pragma("unroll") \
        for (int j_ = 0; j_ < 63; ++j_) { \
            int idx_ = j_ * 256 + t; \
            int col_ = idx_ % WCOLS; \
            int row_ = idx_ / WCOLS; \
            int ch_  = row_ & 31; \
            int sl_  = row_ >> 5; \
            int gr_  = min(max(ybase + sl_, 0), HH - 1); \
            int gc_  = min(max(xcb + col_, 0), WWD - 1); \
            win[ch_ * CSTR + sl_ * WCOLS + col_] = \
                xsrc_[(size_t)ch_ * HWP + gr_ * WWD + gc_]; \
        } \
    } while (0)

#define TAPH(DY, DX, K, H) \
    tap_step<DY, DX>(wq, yg, xg, ybase, xcb, fy, fx, rh, rw, \
        Whi + (K) * OO * CC + fragel + (H) * 32, \
        Wlo + (K) * OO * CC + fragel + (H) * 32, \
        acc0, acc1, acc2, acc3)

    // pass h=0: channels 0..31 (ks=0 of every tap)
    STAGEW(0);
    __syncthreads();
    TAPH(-1, -1, 0, 0); TAPH(-1, 0, 1, 0); TAPH(-1, 1, 2, 0);
    TAPH( 0, -1, 3, 0); TAPH( 0, 0, 4, 0); TAPH( 0, 1, 5, 0);
    TAPH( 1, -1, 6, 0); TAPH( 1, 0, 7, 0); TAPH( 1, 1, 8, 0);
    __syncthreads();
    // pass h=1: channels 32..63 (ks=1 of every tap)
    STAGEW(1);
    __syncthreads();
    TAPH(-1, -1, 0, 1); TAPH(-1, 0, 1, 1); TAPH(-1, 1, 2, 1);
    TAPH( 0, -1, 3, 1); TAPH( 0, 0, 4, 1); TAPH( 0, 1, 5, 1);
    TAPH( 1, -1, 6, 1); TAPH( 1, 0, 7, 1); TAPH( 1, 1, 8, 1);

#undef TAPH
#undef STAGEW

    // epilogue: o = mt*16 + quad*4 + r, pixel = (yg, x0 + pc)
    int pxl = yg * WWD + x0 + pc;
#define EPI(MT, ACCV) do { \
        _Pragma("unroll") \
        for (int r = 0; r < 4; ++r) { \
            int o = (MT) * 16 + quad * 4 + r; \
            float v = ACCV[r] + bias[o]; \
            size_t idx = (size_t)(b * OO + o) * HWP + pxl; \
            if (mode == 1) v = fmaxf(v, 0.f); \
            else           v += resid[idx]; \
            out[idx] = v; \
        } \
    } while (0)
    EPI(0, acc0); EPI(1, acc1); EPI(2, acc2); EPI(3, acc3);
#undef EPI
}

// ---------------------------------------------------------------------------
extern "C" void kernel_launch(void* const* d_in, const int* in_sizes, int n_in,
                              void* d_out, int out_size, void* d_ws, size_t ws_size,
                              hipStream_t stream) {
    const float* x      = (const float*)d_in[0];
    const float* w_off1 = (const float*)d_in[1];
    const float* b_off1 = (const float*)d_in[2];
    const float* W1     = (const float*)d_in[3];
    const float* b1     = (const float*)d_in[4];
    const float* w_off2 = (const float*)d_in[5];
    const float* b_off2 = (const float*)d_in[6];
    const float* W2     = (const float*)d_in[7];
    const float* b2     = (const float*)d_in[8];
    const int*   lo_p   = (const int*)d_in[10];
    const int*   hi_p   = (const int*)d_in[11];
    float* outp = (float*)d_out;

    float* wsf = (float*)d_ws;
    float* t1  = wsf;                               // B*C*HW f32
    unsigned short* Wh1 = (unsigned short*)(t1 + (size_t)BB * CC * HWP);
    unsigned short* Wl1 = Wh1 + OO * CC * 9;        // 36864 each
    unsigned short* Wh2 = Wl1 + OO * CC * 9;
    unsigned short* Wl2 = Wh2 + OO * CC * 9;

    // 1. transpose+split both weight tensors
    wtrans_kernel<<<288, 256, 0, stream>>>(W1, W2, Wh1, Wl1, Wh2, Wl2);

    // 2. layer 1: fused offsets + arconv + relu -> t1
    arconv_kernel<<<1024, 256, 0, stream>>>(x, Wh1, Wl1, b1, w_off1, b_off1,
                                            lo_p, hi_p, nullptr, t1, 1);

    // 3. layer 2: fused offsets + arconv + residual -> out
    arconv_kernel<<<1024, 256, 0, stream>>>(t1, Wh2, Wl2, b2, w_off2, b_off2,
                                            lo_p, hi_p, x, outp, 2);
}